// Round 1
// baseline (396.566 us; speedup 1.0000x reference)
//
#include <hip/hip_runtime.h>
#include <hip/hip_bf16.h>

// ---------------------------------------------------------------------------
// GraphSage forward on MI355X.
// Sizes (fixed): NUM_NODES=100000, D=256, H1=H2=256, C=64, B=4096, F1=25, F2=10
// Pipeline:
//   cvt W1,W2,W3 -> bf16
//   A0[b, 0:256]=emb[T0[b]], A0[b,256:512]=mean_f emb[T1[b,f]]        (bf16)
//   comb[:, :256]   = relu(A0 @ W1^T)                                  (GEMM)
//   per chunk c (4 chunks of 25600 rows):
//     A1c[r,0:256]=emb[T1flat[r]], A1c[r,256:512]=mean_j emb[T2[r,j]]
//     h1c = relu(A1c @ W1^T)
//     comb[:, 256:512] += chunk mean over F1=25 of h1c
//   embd = relu(comb @ W2^T)
//   out  = embd @ W3^T   (fp32)
// ---------------------------------------------------------------------------

typedef __bf16  bf16x8 __attribute__((ext_vector_type(8)));
typedef __bf16  bf16x4 __attribute__((ext_vector_type(4)));
typedef float   f32x4  __attribute__((ext_vector_type(4)));

#define NUM_NODES 100000
#define FEAT      256
#define H1        256
#define H2        256
#define NCLS      64
#define BATCH     4096
#define F1        25
#define F2        10
#define NROWS1    (BATCH * F1)        // 102400
#define CHUNK     25600               // rows per hop-2 chunk (divisible by 128 and 25)
#define NCHUNK    4
#define CB        (CHUNK / F1)        // 1024 batches per chunk

__device__ __forceinline__ uint2 pack4_bf16(float a, float b, float c, float d) {
    union { __bf16 h[4]; uint2 u; } p;
    p.h[0] = (__bf16)a; p.h[1] = (__bf16)b; p.h[2] = (__bf16)c; p.h[3] = (__bf16)d;
    return p.u;
}

// ---- fp32 -> bf16 convert (vectorized) ------------------------------------
__global__ __launch_bounds__(256) void cvt_bf16(const float* __restrict__ in,
                                                __bf16* __restrict__ out, int n4) {
    int i = blockIdx.x * 256 + threadIdx.x;
    if (i < n4) {
        float4 v = reinterpret_cast<const float4*>(in)[i];
        reinterpret_cast<uint2*>(out)[i] = pack4_bf16(v.x, v.y, v.z, v.w);
    }
}

// ---- build A0: [B, 512]  left=emb[T0], right=mean25(emb[T1]) --------------
__global__ __launch_bounds__(256) void build_A0(const int* __restrict__ T0,
                                                const int* __restrict__ T1,
                                                const float* __restrict__ emb,
                                                __bf16* __restrict__ A0) {
    int b    = blockIdx.x * 4 + (threadIdx.x >> 6);   // 4 rows per block
    int lane = threadIdx.x & 63;                      // float4 index (64*4 = 256 cols)
    const float4* e4 = reinterpret_cast<const float4*>(emb);
    int t0 = T0[b];
    float4 L = e4[(size_t)t0 * 64 + lane];
    float sx = 0.f, sy = 0.f, sz = 0.f, sw = 0.f;
    for (int f = 0; f < F1; ++f) {
        int t1 = T1[b * F1 + f];
        float4 v = e4[(size_t)t1 * 64 + lane];
        sx += v.x; sy += v.y; sz += v.z; sw += v.w;
    }
    const float r = 1.0f / (float)F1;
    __bf16* row = A0 + (size_t)b * 512;
    reinterpret_cast<uint2*>(row)[lane]      = pack4_bf16(L.x, L.y, L.z, L.w);
    reinterpret_cast<uint2*>(row + 256)[lane] = pack4_bf16(sx * r, sy * r, sz * r, sw * r);
}

// ---- build A1 chunk: [CHUNK, 512] left=emb[T1flat], right=mean10(emb[T2]) -
__global__ __launch_bounds__(256) void build_A1(const int* __restrict__ T1flat,
                                                const int* __restrict__ T2,
                                                const float* __restrict__ emb,
                                                __bf16* __restrict__ A1c,
                                                int base_row) {
    int rl   = blockIdx.x * 4 + (threadIdx.x >> 6);   // local row in chunk
    int row  = base_row + rl;                         // global row in [0, 102400)
    int lane = threadIdx.x & 63;
    const float4* e4 = reinterpret_cast<const float4*>(emb);
    int t1 = T1flat[row];
    float4 L = e4[(size_t)t1 * 64 + lane];
    float sx = 0.f, sy = 0.f, sz = 0.f, sw = 0.f;
    for (int j = 0; j < F2; ++j) {
        int t2 = T2[(size_t)row * F2 + j];
        float4 v = e4[(size_t)t2 * 64 + lane];
        sx += v.x; sy += v.y; sz += v.z; sw += v.w;
    }
    const float r = 1.0f / (float)F2;
    __bf16* orow = A1c + (size_t)rl * 512;
    reinterpret_cast<uint2*>(orow)[lane]       = pack4_bf16(L.x, L.y, L.z, L.w);
    reinterpret_cast<uint2*>(orow + 256)[lane] = pack4_bf16(sx * r, sy * r, sz * r, sw * r);
}

// ---- GEMM: C = relu(A @ W^T), A[M,K] bf16, W[N,K] bf16, C bf16 (ldc) ------
// grid = (M/128, N/128); 4 waves/block, each wave does a 64x64 tile.
__global__ __launch_bounds__(256) void gemm_relu_bf16(const __bf16* __restrict__ A,
                                                      const __bf16* __restrict__ W,
                                                      __bf16* __restrict__ C,
                                                      int K, int ldc) {
    int wid  = threadIdx.x >> 6;
    int lane = threadIdx.x & 63;
    int m0 = blockIdx.x * 128 + (wid >> 1) * 64;
    int n0 = blockIdx.y * 128 + (wid & 1) * 64;
    int lr = lane & 15;     // row/col within fragment
    int kg = lane >> 4;     // k-group (0..3), 8 contiguous k each

    f32x4 acc[4][4] = {};
    const __bf16* Abase = A + (size_t)(m0 + lr) * K + kg * 8;
    const __bf16* Wbase = W + (size_t)(n0 + lr) * K + kg * 8;

    for (int kt = 0; kt < K; kt += 32) {
        bf16x8 a[4], b[4];
#pragma unroll
        for (int i = 0; i < 4; ++i)
            a[i] = *reinterpret_cast<const bf16x8*>(Abase + (size_t)i * 16 * K + kt);
#pragma unroll
        for (int i = 0; i < 4; ++i)
            b[i] = *reinterpret_cast<const bf16x8*>(Wbase + (size_t)i * 16 * K + kt);
#pragma unroll
        for (int mi = 0; mi < 4; ++mi)
#pragma unroll
            for (int ni = 0; ni < 4; ++ni)
                acc[mi][ni] = __builtin_amdgcn_mfma_f32_16x16x32_bf16(a[mi], b[ni], acc[mi][ni], 0, 0, 0);
    }

    int orow = (lane >> 4) * 4;   // D layout: row=(lane>>4)*4+j, col=lane&15
    int ocol = lane & 15;
#pragma unroll
    for (int mi = 0; mi < 4; ++mi)
#pragma unroll
        for (int ni = 0; ni < 4; ++ni)
#pragma unroll
            for (int j = 0; j < 4; ++j) {
                float v = acc[mi][ni][j];
                v = fmaxf(v, 0.0f);
                C[(size_t)(m0 + mi * 16 + orow + j) * ldc + (n0 + ni * 16 + ocol)] = (__bf16)v;
            }
}

// ---- final GEMM: out = embd @ W3^T, M=4096, N=64, K=256, fp32 out ---------
// grid = M/128; 4 waves/block, each wave 32x64.
__global__ __launch_bounds__(256) void gemm_out(const __bf16* __restrict__ A,
                                                const __bf16* __restrict__ W,
                                                float* __restrict__ C) {
    const int K = 256;
    int wid  = threadIdx.x >> 6;
    int lane = threadIdx.x & 63;
    int m0 = blockIdx.x * 128 + wid * 32;
    int lr = lane & 15;
    int kg = lane >> 4;

    f32x4 acc[2][4] = {};
    const __bf16* Abase = A + (size_t)(m0 + lr) * K + kg * 8;
    const __bf16* Wbase = W + (size_t)lr * K + kg * 8;

    for (int kt = 0; kt < K; kt += 32) {
        bf16x8 a[2], b[4];
#pragma unroll
        for (int i = 0; i < 2; ++i)
            a[i] = *reinterpret_cast<const bf16x8*>(Abase + (size_t)i * 16 * K + kt);
#pragma unroll
        for (int i = 0; i < 4; ++i)
            b[i] = *reinterpret_cast<const bf16x8*>(Wbase + (size_t)i * 16 * K + kt);
#pragma unroll
        for (int mi = 0; mi < 2; ++mi)
#pragma unroll
            for (int ni = 0; ni < 4; ++ni)
                acc[mi][ni] = __builtin_amdgcn_mfma_f32_16x16x32_bf16(a[mi], b[ni], acc[mi][ni], 0, 0, 0);
    }

    int orow = (lane >> 4) * 4;
    int ocol = lane & 15;
#pragma unroll
    for (int mi = 0; mi < 2; ++mi)
#pragma unroll
        for (int ni = 0; ni < 4; ++ni)
#pragma unroll
            for (int j = 0; j < 4; ++j)
                C[(size_t)(m0 + mi * 16 + orow + j) * 64 + (ni * 16 + ocol)] = acc[mi][ni][j];
}

// ---- reduce h1 chunk: comb[b, 256:512] = mean over F1 of relu'd h1 rows ---
__global__ __launch_bounds__(256) void reduce_h1(const __bf16* __restrict__ h1c,
                                                 __bf16* __restrict__ combR) {
    int bl   = blockIdx.x * 4 + (threadIdx.x >> 6);   // local batch in chunk
    int lane = threadIdx.x & 63;
    float s0 = 0.f, s1 = 0.f, s2 = 0.f, s3 = 0.f;
    for (int f = 0; f < F1; ++f) {
        bf16x4 v = *reinterpret_cast<const bf16x4*>(h1c + ((size_t)bl * F1 + f) * 256 + lane * 4);
        s0 += (float)v[0]; s1 += (float)v[1]; s2 += (float)v[2]; s3 += (float)v[3];
    }
    const float r = 1.0f / (float)F1;
    reinterpret_cast<uint2*>(combR + (size_t)bl * 512)[lane] =
        pack4_bf16(s0 * r, s1 * r, s2 * r, s3 * r);
}

extern "C" void kernel_launch(void* const* d_in, const int* in_sizes, int n_in,
                              void* d_out, int out_size, void* d_ws, size_t ws_size,
                              hipStream_t stream) {
    const int*   T0  = (const int*)d_in[0];
    const int*   T1  = (const int*)d_in[1];
    const int*   T2  = (const int*)d_in[2];
    const float* emb = (const float*)d_in[3];
    const float* W1  = (const float*)d_in[4];
    const float* W2  = (const float*)d_in[5];
    const float* W3  = (const float*)d_in[6];
    float* out = (float*)d_out;

    char* ws = (char*)d_ws;
    __bf16* W1b  = (__bf16*)(ws);                       // 256*512*2      = 262144
    __bf16* W2b  = (__bf16*)(ws + 262144);              // 262144
    __bf16* W3b  = (__bf16*)(ws + 524288);              // 64*256*2       = 32768
    __bf16* A0   = (__bf16*)(ws + 557056);              // 4096*512*2     = 4194304
    __bf16* embd = (__bf16*)(ws + 4751360);             // 4096*256*2     = 2097152
    __bf16* comb = (__bf16*)(ws + 6848512);             // 4096*512*2     = 4194304
    __bf16* A1c  = (__bf16*)(ws + 11042816);            // 25600*512*2    = 26214400
    __bf16* h1c  = (__bf16*)(ws + 37257216);            // 25600*256*2    = 13107200
    // total ws use: 50364416 bytes (~50.4 MB)

    // weights -> bf16
    cvt_bf16<<<dim3((131072 / 4 + 255) / 256), dim3(256), 0, stream>>>(W1, W1b, 131072 / 4);
    cvt_bf16<<<dim3((131072 / 4 + 255) / 256), dim3(256), 0, stream>>>(W2, W2b, 131072 / 4);
    cvt_bf16<<<dim3((16384 / 4 + 255) / 256), dim3(256), 0, stream>>>(W3, W3b, 16384 / 4);

    // hop-0 branch
    build_A0<<<dim3(BATCH / 4), dim3(256), 0, stream>>>(T0, T1, emb, A0);
    gemm_relu_bf16<<<dim3(BATCH / 128, 2), dim3(256), 0, stream>>>(A0, W1b, comb, 512, 512);

    // hop-1/2 branch, chunked
    for (int c = 0; c < NCHUNK; ++c) {
        build_A1<<<dim3(CHUNK / 4), dim3(256), 0, stream>>>(T1, T2, emb, A1c, c * CHUNK);
        gemm_relu_bf16<<<dim3(CHUNK / 128, 2), dim3(256), 0, stream>>>(A1c, W1b, h1c, 512, 256);
        reduce_h1<<<dim3(CB / 4), dim3(256), 0, stream>>>(h1c, comb + (size_t)c * CB * 512 + 256);
    }

    // layer 2 + classifier
    gemm_relu_bf16<<<dim3(BATCH / 128, 2), dim3(256), 0, stream>>>(comb, W2b, embd, 512, 256);
    gemm_out<<<dim3(BATCH / 128), dim3(256), 0, stream>>>(embd, W3b, out);
}

// Round 2
// 210.443 us; speedup vs baseline: 1.8844x; 1.8844x over previous
//
#include <hip/hip_runtime.h>
#include <hip/hip_bf16.h>

// ---------------------------------------------------------------------------
// GraphSage forward on MI355X — round 2.
//   cvt W1,W2,W3 -> bf16; cvt emb -> bf16 (embB, 51.2MB, L3-resident)
//   build_A0 (bf16 gather) ; comb[:, :256] = relu(A0 @ W1^T)
//   fused_h1: per 64-row tile, gather [64x512] bf16 A-tile into swizzled LDS,
//             GEMM vs W1^T (N=256 in one block) -> h1 [102400, 256]
//   reduce_h1: comb[:, 256:512] = mean over F1=25
//   embd = relu(comb @ W2^T); out = embd @ W3^T (fp32)
// ---------------------------------------------------------------------------

typedef __bf16  bf16x8 __attribute__((ext_vector_type(8)));
typedef __bf16  bf16x4 __attribute__((ext_vector_type(4)));
typedef float   f32x4  __attribute__((ext_vector_type(4)));

#define FEAT      256
#define BATCH     4096
#define F1        25
#define F2        10
#define NROWS1    (BATCH * F1)        // 102400
#define EMB_ELEMS (100000 * 256)      // 25,600,000

__device__ __forceinline__ uint2 pack4_bf16(float a, float b, float c, float d) {
    union { __bf16 h[4]; uint2 u; } p;
    p.h[0] = (__bf16)a; p.h[1] = (__bf16)b; p.h[2] = (__bf16)c; p.h[3] = (__bf16)d;
    return p.u;
}

// LDS swizzle for a [64][512] bf16 tile (1024 B/row): spread the 16-row
// column stack across 8 distinct 16B slots. byte ^= (row&7)<<4.
__device__ __forceinline__ int swz(int row, int colbyte) {
    return row * 1024 + (colbyte ^ ((row & 7) << 4));
}

// ---- fp32 -> bf16 (8 elems/thread) ----------------------------------------
__global__ __launch_bounds__(256) void cvt_bf16_8(const float* __restrict__ in,
                                                  __bf16* __restrict__ out, int n8) {
    int i = blockIdx.x * 256 + threadIdx.x;
    if (i < n8) {
        float4 v0 = reinterpret_cast<const float4*>(in)[i * 2];
        float4 v1 = reinterpret_cast<const float4*>(in)[i * 2 + 1];
        uint4 o;
        uint2 a = pack4_bf16(v0.x, v0.y, v0.z, v0.w);
        uint2 b = pack4_bf16(v1.x, v1.y, v1.z, v1.w);
        o.x = a.x; o.y = a.y; o.z = b.x; o.w = b.y;
        reinterpret_cast<uint4*>(out)[i] = o;
    }
}

// ---- build A0: [B, 512]  left=embB[T0], right=mean25(embB[T1]) ------------
__global__ __launch_bounds__(256) void build_A0(const int* __restrict__ T0,
                                                const int* __restrict__ T1,
                                                const __bf16* __restrict__ embB,
                                                __bf16* __restrict__ A0) {
    int b    = blockIdx.x * 4 + (threadIdx.x >> 6);
    int lane = threadIdx.x & 63;           // bf16x4 index (64*4 = 256 cols)
    int t0 = T0[b];
    bf16x4 L = *reinterpret_cast<const bf16x4*>(embB + (size_t)t0 * 256 + lane * 4);
    float s0 = 0.f, s1 = 0.f, s2 = 0.f, s3 = 0.f;
    for (int f = 0; f < F1; ++f) {
        int t1 = T1[b * F1 + f];
        bf16x4 v = *reinterpret_cast<const bf16x4*>(embB + (size_t)t1 * 256 + lane * 4);
        s0 += (float)v[0]; s1 += (float)v[1]; s2 += (float)v[2]; s3 += (float)v[3];
    }
    const float r = 1.0f / (float)F1;
    __bf16* row = A0 + (size_t)b * 512;
    *reinterpret_cast<bf16x4*>(row + lane * 4) = L;
    reinterpret_cast<uint2*>(row + 256)[lane] = pack4_bf16(s0 * r, s1 * r, s2 * r, s3 * r);
}

// ---- fused hop-1/2: gather A-tile into LDS + GEMM vs W1^T -----------------
// grid.x = NROWS1/64 = 1600; 256 threads (4 waves), block tile 64(M) x 256(N).
__global__ __launch_bounds__(256) void fused_h1(const int* __restrict__ T1,
                                                const int* __restrict__ T2,
                                                const __bf16* __restrict__ embB,
                                                const __bf16* __restrict__ W1b,
                                                __bf16* __restrict__ h1) {
    __shared__ __align__(16) char At[64 * 1024];   // 64 rows x 512 bf16, swizzled
    const int tid = threadIdx.x;
    const int m0  = blockIdx.x * 64;

    // ---- gather phase: 16 lanes per row, 16 rows in parallel, 4 iters ----
    {
        const int lane16 = tid & 15;
        const int rgrp   = tid >> 4;
        const int cb     = lane16 * 32;            // byte col within 512B half
#pragma unroll
        for (int it = 0; it < 4; ++it) {
            const int rl   = it * 16 + rgrp;
            const int grow = m0 + rl;
            const int t1   = T1[grow];
            const __bf16* src = embB + (size_t)t1 * 256 + lane16 * 16;
            bf16x8 L0 = *reinterpret_cast<const bf16x8*>(src);
            bf16x8 L1 = *reinterpret_cast<const bf16x8*>(src + 8);
            *reinterpret_cast<bf16x8*>(At + swz(rl, cb))      = L0;
            *reinterpret_cast<bf16x8*>(At + swz(rl, cb + 16)) = L1;
            float acc[16];
#pragma unroll
            for (int e = 0; e < 16; ++e) acc[e] = 0.f;
            for (int j = 0; j < F2; ++j) {
                const int t2 = T2[(size_t)grow * F2 + j];
                const __bf16* s2 = embB + (size_t)t2 * 256 + lane16 * 16;
                bf16x8 v0 = *reinterpret_cast<const bf16x8*>(s2);
                bf16x8 v1 = *reinterpret_cast<const bf16x8*>(s2 + 8);
#pragma unroll
                for (int e = 0; e < 8; ++e) { acc[e] += (float)v0[e]; acc[8 + e] += (float)v1[e]; }
            }
            bf16x8 R0, R1;
#pragma unroll
            for (int e = 0; e < 8; ++e) {
                R0[e] = (__bf16)(acc[e] * 0.1f);
                R1[e] = (__bf16)(acc[8 + e] * 0.1f);
            }
            *reinterpret_cast<bf16x8*>(At + swz(rl, 512 + cb))      = R0;
            *reinterpret_cast<bf16x8*>(At + swz(rl, 512 + cb + 16)) = R1;
        }
    }
    __syncthreads();

    // ---- GEMM phase: wave wid covers cols n0..n0+63, rows m0..m0+63 ------
    const int wid  = tid >> 6;
    const int lane = tid & 63;
    const int n0   = wid * 64;
    const int lr   = lane & 15;
    const int kg   = lane >> 4;

    f32x4 acc[4][4] = {};
    const __bf16* Wbase = W1b + (size_t)(n0 + lr) * 512 + kg * 8;

    for (int kt = 0; kt < 512; kt += 32) {
        bf16x8 a[4], b[4];
#pragma unroll
        for (int i = 0; i < 4; ++i)
            a[i] = *reinterpret_cast<const bf16x8*>(At + swz(lr + i * 16, kt * 2 + kg * 16));
#pragma unroll
        for (int i = 0; i < 4; ++i)
            b[i] = *reinterpret_cast<const bf16x8*>(Wbase + (size_t)i * 16 * 512 + kt);
#pragma unroll
        for (int mi = 0; mi < 4; ++mi)
#pragma unroll
            for (int ni = 0; ni < 4; ++ni)
                acc[mi][ni] = __builtin_amdgcn_mfma_f32_16x16x32_bf16(a[mi], b[ni], acc[mi][ni], 0, 0, 0);
    }

    const int orow = (lane >> 4) * 4;
    const int ocol = lane & 15;
#pragma unroll
    for (int mi = 0; mi < 4; ++mi)
#pragma unroll
        for (int ni = 0; ni < 4; ++ni)
#pragma unroll
            for (int j = 0; j < 4; ++j) {
                float v = fmaxf(acc[mi][ni][j], 0.0f);
                h1[(size_t)(m0 + mi * 16 + orow + j) * 256 + (n0 + ni * 16 + ocol)] = (__bf16)v;
            }
}

// ---- GEMM: C = relu(A @ W^T), A[M,K] bf16, W[N,K] bf16, C bf16 (ldc) ------
__global__ __launch_bounds__(256) void gemm_relu_bf16(const __bf16* __restrict__ A,
                                                      const __bf16* __restrict__ W,
                                                      __bf16* __restrict__ C,
                                                      int K, int ldc) {
    int wid  = threadIdx.x >> 6;
    int lane = threadIdx.x & 63;
    int m0 = blockIdx.x * 128 + (wid >> 1) * 64;
    int n0 = blockIdx.y * 128 + (wid & 1) * 64;
    int lr = lane & 15;
    int kg = lane >> 4;

    f32x4 acc[4][4] = {};
    const __bf16* Abase = A + (size_t)(m0 + lr) * K + kg * 8;
    const __bf16* Wbase = W + (size_t)(n0 + lr) * K + kg * 8;

    for (int kt = 0; kt < K; kt += 32) {
        bf16x8 a[4], b[4];
#pragma unroll
        for (int i = 0; i < 4; ++i)
            a[i] = *reinterpret_cast<const bf16x8*>(Abase + (size_t)i * 16 * K + kt);
#pragma unroll
        for (int i = 0; i < 4; ++i)
            b[i] = *reinterpret_cast<const bf16x8*>(Wbase + (size_t)i * 16 * K + kt);
#pragma unroll
        for (int mi = 0; mi < 4; ++mi)
#pragma unroll
            for (int ni = 0; ni < 4; ++ni)
                acc[mi][ni] = __builtin_amdgcn_mfma_f32_16x16x32_bf16(a[mi], b[ni], acc[mi][ni], 0, 0, 0);
    }

    int orow = (lane >> 4) * 4;
    int ocol = lane & 15;
#pragma unroll
    for (int mi = 0; mi < 4; ++mi)
#pragma unroll
        for (int ni = 0; ni < 4; ++ni)
#pragma unroll
            for (int j = 0; j < 4; ++j) {
                float v = fmaxf(acc[mi][ni][j], 0.0f);
                C[(size_t)(m0 + mi * 16 + orow + j) * ldc + (n0 + ni * 16 + ocol)] = (__bf16)v;
            }
}

// ---- final GEMM: out = embd @ W3^T, M=4096, N=64, K=256, fp32 out ---------
__global__ __launch_bounds__(256) void gemm_out(const __bf16* __restrict__ A,
                                                const __bf16* __restrict__ W,
                                                float* __restrict__ C) {
    const int K = 256;
    int wid  = threadIdx.x >> 6;
    int lane = threadIdx.x & 63;
    int m0 = blockIdx.x * 128 + wid * 32;
    int lr = lane & 15;
    int kg = lane >> 4;

    f32x4 acc[2][4] = {};
    const __bf16* Abase = A + (size_t)(m0 + lr) * K + kg * 8;
    const __bf16* Wbase = W + (size_t)lr * K + kg * 8;

    for (int kt = 0; kt < K; kt += 32) {
        bf16x8 a[2], b[4];
#pragma unroll
        for (int i = 0; i < 2; ++i)
            a[i] = *reinterpret_cast<const bf16x8*>(Abase + (size_t)i * 16 * K + kt);
#pragma unroll
        for (int i = 0; i < 4; ++i)
            b[i] = *reinterpret_cast<const bf16x8*>(Wbase + (size_t)i * 16 * K + kt);
#pragma unroll
        for (int mi = 0; mi < 2; ++mi)
#pragma unroll
            for (int ni = 0; ni < 4; ++ni)
                acc[mi][ni] = __builtin_amdgcn_mfma_f32_16x16x32_bf16(a[mi], b[ni], acc[mi][ni], 0, 0, 0);
    }

    int orow = (lane >> 4) * 4;
    int ocol = lane & 15;
#pragma unroll
    for (int mi = 0; mi < 2; ++mi)
#pragma unroll
        for (int ni = 0; ni < 4; ++ni)
#pragma unroll
            for (int j = 0; j < 4; ++j)
                C[(size_t)(m0 + mi * 16 + orow + j) * 64 + (ni * 16 + ocol)] = acc[mi][ni][j];
}

// ---- reduce h1: comb[b, 256:512] = mean over F1 of h1 rows ----------------
__global__ __launch_bounds__(256) void reduce_h1(const __bf16* __restrict__ h1,
                                                 __bf16* __restrict__ combR) {
    int b    = blockIdx.x * 4 + (threadIdx.x >> 6);
    int lane = threadIdx.x & 63;
    float s0 = 0.f, s1 = 0.f, s2 = 0.f, s3 = 0.f;
    for (int f = 0; f < F1; ++f) {
        bf16x4 v = *reinterpret_cast<const bf16x4*>(h1 + ((size_t)b * F1 + f) * 256 + lane * 4);
        s0 += (float)v[0]; s1 += (float)v[1]; s2 += (float)v[2]; s3 += (float)v[3];
    }
    const float r = 1.0f / (float)F1;
    reinterpret_cast<uint2*>(combR + (size_t)b * 512)[lane] =
        pack4_bf16(s0 * r, s1 * r, s2 * r, s3 * r);
}

extern "C" void kernel_launch(void* const* d_in, const int* in_sizes, int n_in,
                              void* d_out, int out_size, void* d_ws, size_t ws_size,
                              hipStream_t stream) {
    const int*   T0  = (const int*)d_in[0];
    const int*   T1  = (const int*)d_in[1];
    const int*   T2  = (const int*)d_in[2];
    const float* emb = (const float*)d_in[3];
    const float* W1  = (const float*)d_in[4];
    const float* W2  = (const float*)d_in[5];
    const float* W3  = (const float*)d_in[6];
    float* out = (float*)d_out;

    char* ws = (char*)d_ws;
    __bf16* W1b  = (__bf16*)(ws);                  //   262144
    __bf16* W2b  = (__bf16*)(ws + 262144);         //   262144
    __bf16* W3b  = (__bf16*)(ws + 524288);         //    32768
    __bf16* A0   = (__bf16*)(ws + 557056);         //  4194304
    __bf16* embd = (__bf16*)(ws + 4751360);        //  2097152
    __bf16* comb = (__bf16*)(ws + 6848512);        //  4194304
    __bf16* embB = (__bf16*)(ws + 11042816);       // 51200000
    __bf16* h1   = (__bf16*)(ws + 62242816);       // 52428800 -> ends 114671616

    // weights + emb -> bf16
    cvt_bf16_8<<<dim3(131072 / 8 / 256), dim3(256), 0, stream>>>(W1, W1b, 131072 / 8);
    cvt_bf16_8<<<dim3(131072 / 8 / 256), dim3(256), 0, stream>>>(W2, W2b, 131072 / 8);
    cvt_bf16_8<<<dim3(16384 / 8 / 256), dim3(256), 0, stream>>>(W3, W3b, 16384 / 8);
    cvt_bf16_8<<<dim3(EMB_ELEMS / 8 / 256), dim3(256), 0, stream>>>(emb, embB, EMB_ELEMS / 8);

    // hop-0 branch
    build_A0<<<dim3(BATCH / 4), dim3(256), 0, stream>>>(T0, T1, embB, A0);
    gemm_relu_bf16<<<dim3(BATCH / 128, 2), dim3(256), 0, stream>>>(A0, W1b, comb, 512, 512);

    // hop-1/2 branch: fused gather + GEMM, then mean over F1
    fused_h1<<<dim3(NROWS1 / 64), dim3(256), 0, stream>>>(T1, T2, embB, W1b, h1);
    reduce_h1<<<dim3(BATCH / 4), dim3(256), 0, stream>>>(h1, comb + 256);

    // layer 2 + classifier
    gemm_relu_bf16<<<dim3(BATCH / 128, 2), dim3(256), 0, stream>>>(comb, W2b, embd, 512, 256);
    gemm_out<<<dim3(BATCH / 128), dim3(256), 0, stream>>>(embd, W3b, out);
}